// Round 15
// baseline (263.287 us; speedup 1.0000x reference)
//
#include <hip/hip_runtime.h>
#include <math.h>

#define FFT_N 16384
#define NT 1024          // 16 waves/block -> 45% occupancy (proven reachable, R3)
#define B_DIM 8
#define H_DIM 256

// Single float2 plane (128 KiB), b64 DS ops. Swizzle xors bits0-3 with bits5-8
// and bit0 with bit9: bijective, leaves bits>=10 (wave regions of 1024) intact.
// Hand-checked <=4 lanes/bank-pair (b64 capacity) for all maps below.
#define SWZ2(a) ((a) ^ (((a) >> 5) & 15) ^ (((a) >> 9) & 1))

// Maps (thread t, wave w=t>>6 owns region [1024w,1024w+1024), lane l=t&63):
//  nA: e    = t + 1024*m          (global stages, cross-region)
//  W1: eloc = 64*jj + l           (stages q=256,64)
//  W2: eloc = 64*(l>>2)+4*jj+(l&3)(stages q=16,4)
//  W3: eloc = 16*l + jj           (stage q=1; flat = 16t+jj contiguous)
// Wave-local phases need no fences (per-wave DS in-order, HW-validated R13);
// only the two cross-region exchanges (entry/exit) use __syncthreads.

__device__ __forceinline__ float2 cmul(float2 a, float2 b) {
    return make_float2(a.x * b.x - a.y * b.y, a.x * b.y + a.y * b.x);
}
__device__ __forceinline__ float2 cadd(float2 a, float2 b) { return make_float2(a.x + b.x, a.y + b.y); }
__device__ __forceinline__ float2 csub(float2 a, float2 b) { return make_float2(a.x - b.x, a.y - b.y); }
__device__ __forceinline__ float2 mulnegi(float2 z) { return make_float2(z.y, -z.x); }   // -i*z
__device__ __forceinline__ float2 mulposi(float2 z) { return make_float2(-z.y, z.x); }   // +i*z

// ---- radix-4 butterflies (verified R1..R14) ----
__device__ __forceinline__ void bfly4(float2& a, float2& b, float2& c, float2& d,
                                      float2 w1, float2 w2, float2 w3) {
    float2 apc = cadd(a, c), amc = csub(a, c);
    float2 bpd = cadd(b, d), bmd = csub(b, d);
    float2 nib = mulnegi(bmd);
    a = cadd(apc, bpd);
    b = cmul(csub(apc, bpd), w2);
    c = cmul(cadd(amc, nib), w1);
    d = cmul(csub(amc, nib), w3);
}
__device__ __forceinline__ void bfly4_nw(float2& a, float2& b, float2& c, float2& d) {
    float2 apc = cadd(a, c), amc = csub(a, c);
    float2 bpd = cadd(b, d), bmd = csub(b, d);
    float2 nib = mulnegi(bmd);
    a = cadd(apc, bpd);
    b = csub(apc, bpd);
    c = cadd(amc, nib);
    d = csub(amc, nib);
}
__device__ __forceinline__ void ibfly4(float2& a, float2& b, float2& c, float2& d,
                                       float2 w1t, float2 w2t) {
    float2 w1 = make_float2(w1t.x, -w1t.y);
    float2 w2 = make_float2(w2t.x, -w2t.y);
    float2 bt = cmul(b, w2), dt = cmul(d, w2);
    float2 A = cadd(a, bt), Bb = csub(a, bt);
    float2 C = cadd(c, dt), Dd = csub(c, dt);
    float2 Cw = cmul(C, w1);
    float2 Dw = mulposi(cmul(Dd, w1));
    a = cadd(A, Cw);  c = csub(A, Cw);
    b = cadd(Bb, Dw); d = csub(Bb, Dw);
}
__device__ __forceinline__ void ibfly4_nw(float2& a, float2& b, float2& c, float2& d) {
    float2 A = cadd(a, b), Bb = csub(a, b);
    float2 C = cadd(c, d), Dd = csub(c, d);
    float2 Dw = mulposi(Dd);
    a = cadd(A, C);  c = csub(A, C);
    b = cadd(Bb, Dw); d = csub(Bb, Dw);
}

// ---- global stages 0,1 on r[16] (NT=1024: quads in-thread; same twiddle algebra) ----
__device__ __forceinline__ void fwd_g01(float2 r[16], const int t,
                                        const float2* __restrict__ tw) {
#pragma unroll
    for (int m0 = 0; m0 < 4; ++m0) {
        const int i = t + 1024 * m0;                      // e of quad head (= e mod 4096)
        bfly4(r[m0], r[m0 + 4], r[m0 + 8], r[m0 + 12], tw[i], tw[2 * i], tw[3 * i]);
    }
    {
        const int ig = 4 * t;                             // uniform over the 4 quads
        const float2 w1 = tw[ig], w2 = tw[2 * ig], w3 = tw[3 * ig];
#pragma unroll
        for (int a = 0; a < 4; ++a)
            bfly4(r[4 * a], r[4 * a + 1], r[4 * a + 2], r[4 * a + 3], w1, w2, w3);
    }
}
__device__ __forceinline__ void inv_g01(float2 r[16], const int t,
                                        const float2* __restrict__ tw) {
    {
        const int ig = 4 * t;
        const float2 w1 = tw[ig], w2 = tw[2 * ig];
#pragma unroll
        for (int a = 0; a < 4; ++a)
            ibfly4(r[4 * a], r[4 * a + 1], r[4 * a + 2], r[4 * a + 3], w1, w2);
    }
#pragma unroll
    for (int m0 = 0; m0 < 4; ++m0) {
        const int i = t + 1024 * m0;
        ibfly4(r[m0], r[m0 + 4], r[m0 + 8], r[m0 + 12], tw[i], tw[2 * i]);
    }
}

__device__ __forceinline__ float ftanh(float x) {
    float e = __expf(2.0f * x);
    return 1.0f - 2.0f * __builtin_amdgcn_rcpf(e + 1.0f);
}

__global__ void twiddle_init(float2* __restrict__ tw) {
    int t = blockIdx.x * blockDim.x + threadIdx.x;
    if (t < FFT_N) {
        float ang = -2.0f * 3.14159265358979323846f * (float)t / (float)FFT_N;
        float sv, cv;
        sincosf(ang, &sv, &cv);
        tw[t] = make_float2(cv, sv);
    }
}

// Forward FFT of (k_h + dh*delta) -> Kf[h], thread-linear W3 order (16t+jj),
// PRE-SCALED by 1/N (verified R12/R13).
__global__ __launch_bounds__(NT) void kfft_kernel(const float* __restrict__ k,
                                                  const float* __restrict__ D,
                                                  const float2* __restrict__ tw,
                                                  float2* __restrict__ Kf) {
    __shared__ float2 lds2[FFT_N];   // 131072 B
    const int h = blockIdx.x;
    const int t = threadIdx.x;
    const int w = t >> 6, l = t & 63;
    const int base = 1024 * w;
    const int lo = 64 * (l >> 2) + (l & 3);
    const float* krow = k + (size_t)h * FFT_N;

    float2 r[16];
#pragma unroll
    for (int m = 0; m < 16; ++m) r[m] = make_float2(krow[t + 1024 * m], 0.f);
    if (t == 0) r[0].x += D[h * (H_DIM + 1)];   // fold diag(D) into k's 0th tap
    fwd_g01(r, t, tw);
#pragma unroll
    for (int m = 0; m < 16; ++m) lds2[SWZ2(t + 1024 * m)] = r[m];
    __syncthreads();

    // Phase A: W1, fwd q=256 then q=64
#pragma unroll
    for (int jj = 0; jj < 16; ++jj) r[jj] = lds2[SWZ2(base + 64 * jj + l)];
#pragma unroll
    for (int j0 = 0; j0 < 4; ++j0) {
        const int i1 = 1024 * j0 + 16 * l;
        bfly4(r[j0], r[j0 + 4], r[j0 + 8], r[j0 + 12], tw[i1], tw[2 * i1], tw[3 * i1]);
    }
    {
        const int i2 = 64 * l;
        const float2 w1 = tw[i2], w2 = tw[2 * i2], w3 = tw[3 * i2];
#pragma unroll
        for (int g = 0; g < 4; ++g)
            bfly4(r[4 * g], r[4 * g + 1], r[4 * g + 2], r[4 * g + 3], w1, w2, w3);
    }
#pragma unroll
    for (int jj = 0; jj < 16; ++jj) lds2[SWZ2(base + 64 * jj + l)] = r[jj];

    // Phase B: W2, fwd q=16 then q=4
#pragma unroll
    for (int jj = 0; jj < 16; ++jj) r[jj] = lds2[SWZ2(base + lo + 4 * jj)];
#pragma unroll
    for (int j0 = 0; j0 < 4; ++j0) {
        const int i3 = 1024 * j0 + 256 * (l & 3);
        bfly4(r[j0], r[j0 + 4], r[j0 + 8], r[j0 + 12], tw[i3], tw[2 * i3], tw[3 * i3]);
    }
    {
        const int i4 = 1024 * (l & 3);
        const float2 w1 = tw[i4], w2 = tw[2 * i4], w3 = tw[3 * i4];
#pragma unroll
        for (int g = 0; g < 4; ++g)
            bfly4(r[4 * g], r[4 * g + 1], r[4 * g + 2], r[4 * g + 3], w1, w2, w3);
    }
#pragma unroll
    for (int jj = 0; jj < 16; ++jj) lds2[SWZ2(base + lo + 4 * jj)] = r[jj];

    // Phase C (fwd tail): W3, q=1, scale, store
#pragma unroll
    for (int jj = 0; jj < 16; ++jj) r[jj] = lds2[SWZ2(base + 16 * l + jj)];
#pragma unroll
    for (int g = 0; g < 4; ++g)
        bfly4_nw(r[4 * g], r[4 * g + 1], r[4 * g + 2], r[4 * g + 3]);
    const float invN = 1.0f / (float)FFT_N;
    float4* out4 = (float4*)(Kf + (size_t)h * FFT_N);
#pragma unroll
    for (int q = 0; q < 8; ++q)
        out4[8 * t + q] = make_float4(r[2 * q].x * invN, r[2 * q].y * invN,
                                      r[2 * q + 1].x * invN, r[2 * q + 1].y * invN);
}

// Batch rows (2p,h) and (2p+1,h) packed as z = u0 + i*u1.
__global__ __launch_bounds__(NT) void conv_kernel(const float* __restrict__ u,
                                                  const float2* __restrict__ tw,
                                                  const float2* __restrict__ Kf,
                                                  float* __restrict__ out) {
    __shared__ float2 lds2[FFT_N];   // 131072 B
    const int raw = blockIdx.x;
    const int vb = ((raw & 7) << 7) + (raw >> 3);   // XCD-chunked bijection
    const int h = vb >> 2;
    const int p = vb & 3;
    const int t = threadIdx.x;
    const int w = t >> 6, l = t & 63;
    const int base = 1024 * w;
    const int lo = 64 * (l >> 2) + (l & 3);
    const size_t row0 = ((size_t)(2 * p) * H_DIM + h) * FFT_N;
    const size_t row1 = row0 + (size_t)H_DIM * FFT_N;
    const float* u0 = u + row0;
    const float* u1 = u + row1;

    // entry: load, g01 (in-thread), cross-region exchange
    float2 r[16];
#pragma unroll
    for (int m = 0; m < 16; ++m) {
        const int e = t + 1024 * m;
        r[m] = make_float2(u0[e], u1[e]);
    }
    fwd_g01(r, t, tw);
#pragma unroll
    for (int m = 0; m < 16; ++m) lds2[SWZ2(t + 1024 * m)] = r[m];
    __syncthreads();

    // Phase A: W1, fwd q=256 then q=64 (wave-local, no fence)
#pragma unroll
    for (int jj = 0; jj < 16; ++jj) r[jj] = lds2[SWZ2(base + 64 * jj + l)];
#pragma unroll
    for (int j0 = 0; j0 < 4; ++j0) {
        const int i1 = 1024 * j0 + 16 * l;
        bfly4(r[j0], r[j0 + 4], r[j0 + 8], r[j0 + 12], tw[i1], tw[2 * i1], tw[3 * i1]);
    }
    {
        const int i2 = 64 * l;
        const float2 w1 = tw[i2], w2 = tw[2 * i2], w3 = tw[3 * i2];
#pragma unroll
        for (int g = 0; g < 4; ++g)
            bfly4(r[4 * g], r[4 * g + 1], r[4 * g + 2], r[4 * g + 3], w1, w2, w3);
    }
#pragma unroll
    for (int jj = 0; jj < 16; ++jj) lds2[SWZ2(base + 64 * jj + l)] = r[jj];

    // Phase B: W2, fwd q=16 then q=4
#pragma unroll
    for (int jj = 0; jj < 16; ++jj) r[jj] = lds2[SWZ2(base + lo + 4 * jj)];
#pragma unroll
    for (int j0 = 0; j0 < 4; ++j0) {
        const int i3 = 1024 * j0 + 256 * (l & 3);
        bfly4(r[j0], r[j0 + 4], r[j0 + 8], r[j0 + 12], tw[i3], tw[2 * i3], tw[3 * i3]);
    }
    {
        const int i4 = 1024 * (l & 3);
        const float2 w1 = tw[i4], w2 = tw[2 * i4], w3 = tw[3 * i4];
#pragma unroll
        for (int g = 0; g < 4; ++g)
            bfly4(r[4 * g], r[4 * g + 1], r[4 * g + 2], r[4 * g + 3], w1, w2, w3);
    }
#pragma unroll
    for (int jj = 0; jj < 16; ++jj) lds2[SWZ2(base + lo + 4 * jj)] = r[jj];

    // Phase C: W3, fwd q=1, pointwise (Kf pre-scaled), inv q=1
#pragma unroll
    for (int jj = 0; jj < 16; ++jj) r[jj] = lds2[SWZ2(base + 16 * l + jj)];
#pragma unroll
    for (int g = 0; g < 4; ++g)
        bfly4_nw(r[4 * g], r[4 * g + 1], r[4 * g + 2], r[4 * g + 3]);
    {
        const float4* kf4 = (const float4*)(Kf + (size_t)h * FFT_N);
#pragma unroll
        for (int q = 0; q < 8; ++q) {
            const float4 kq = kf4[8 * t + q];
            float2 z;
            z = r[2 * q];
            r[2 * q]     = make_float2(z.x * kq.x - z.y * kq.y, z.x * kq.y + z.y * kq.x);
            z = r[2 * q + 1];
            r[2 * q + 1] = make_float2(z.x * kq.z - z.y * kq.w, z.x * kq.w + z.y * kq.z);
        }
    }
#pragma unroll
    for (int g = 0; g < 4; ++g)
        ibfly4_nw(r[4 * g], r[4 * g + 1], r[4 * g + 2], r[4 * g + 3]);
#pragma unroll
    for (int jj = 0; jj < 16; ++jj) lds2[SWZ2(base + 16 * l + jj)] = r[jj];

    // Phase D: W2, inv q=4 then q=16
#pragma unroll
    for (int jj = 0; jj < 16; ++jj) r[jj] = lds2[SWZ2(base + lo + 4 * jj)];
    {
        const int i4 = 1024 * (l & 3);
        const float2 w1 = tw[i4], w2 = tw[2 * i4];
#pragma unroll
        for (int g = 0; g < 4; ++g)
            ibfly4(r[4 * g], r[4 * g + 1], r[4 * g + 2], r[4 * g + 3], w1, w2);
    }
#pragma unroll
    for (int j0 = 0; j0 < 4; ++j0) {
        const int i3 = 1024 * j0 + 256 * (l & 3);
        ibfly4(r[j0], r[j0 + 4], r[j0 + 8], r[j0 + 12], tw[i3], tw[2 * i3]);
    }
#pragma unroll
    for (int jj = 0; jj < 16; ++jj) lds2[SWZ2(base + lo + 4 * jj)] = r[jj];

    // Phase E: W1, inv q=64 then q=256
#pragma unroll
    for (int jj = 0; jj < 16; ++jj) r[jj] = lds2[SWZ2(base + 64 * jj + l)];
    {
        const int i2 = 64 * l;
        const float2 w1 = tw[i2], w2 = tw[2 * i2];
#pragma unroll
        for (int g = 0; g < 4; ++g)
            ibfly4(r[4 * g], r[4 * g + 1], r[4 * g + 2], r[4 * g + 3], w1, w2);
    }
#pragma unroll
    for (int j0 = 0; j0 < 4; ++j0) {
        const int i1 = 1024 * j0 + 16 * l;
        ibfly4(r[j0], r[j0 + 4], r[j0 + 8], r[j0 + 12], tw[i1], tw[2 * i1]);
    }
#pragma unroll
    for (int jj = 0; jj < 16; ++jj) lds2[SWZ2(base + 64 * jj + l)] = r[jj];
    __syncthreads();

    // exit: cross-region read, inv g01 (in-thread), tanh, store
#pragma unroll
    for (int m = 0; m < 16; ++m) r[m] = lds2[SWZ2(t + 1024 * m)];
    inv_g01(r, t, tw);
    float* o0 = out + row0;
    float* o1 = out + row1;
#pragma unroll
    for (int m = 0; m < 16; ++m) {
        const int e = t + 1024 * m;
        o0[e] = ftanh(r[m].x);
        o1[e] = ftanh(r[m].y);
    }
}

extern "C" void kernel_launch(void* const* d_in, const int* in_sizes, int n_in,
                              void* d_out, int out_size, void* d_ws, size_t ws_size,
                              hipStream_t stream) {
    const float* u = (const float*)d_in[0];   // (B,H,L) f32
    const float* k = (const float*)d_in[1];   // (H,L)   f32
    const float* D = (const float*)d_in[2];   // (H,H)   f32
    float* out = (float*)d_out;

    float2* tw = (float2*)d_ws;               // 16384 float2 = 128 KiB
    float2* Kf = tw + FFT_N;                  // 256*16384 float2 = 32 MiB

    twiddle_init<<<FFT_N / 256, 256, 0, stream>>>(tw);
    kfft_kernel<<<H_DIM, NT, 0, stream>>>(k, D, tw, Kf);
    conv_kernel<<<(B_DIM / 2) * H_DIM, NT, 0, stream>>>(u, tw, Kf, out);
}

// Round 16
// 203.376 us; speedup vs baseline: 1.2946x; 1.2946x over previous
//
#include <hip/hip_runtime.h>
#include <math.h>

#define FFT_N 16384
#define NT 512
#define B_DIM 8
#define H_DIM 256

typedef float v2f __attribute__((ext_vector_type(2)));
__device__ __forceinline__ v2f mk2(float x, float y) { v2f r; r.x = x; r.y = y; return r; }

// Single v2f plane (128 KiB), b64 DS ops (R14-verified swizzle/maps).
#define SWZ2(a) ((a) ^ (((a) >> 5) & 15) ^ (((a) >> 9) & 1))

// No wave-local fences (per-wave DS in-order, HW-validated R13); the two
// cross-region exchanges keep __syncthreads.

// ---- complex arithmetic on packed v2f (identical math to R1..R14 float2) ----
__device__ __forceinline__ v2f cmul(v2f a, v2f b) {
    // (a.x*b.x - a.y*b.y, a.x*b.y + a.y*b.x) = a.xx*b + a.yy*(-b.y, b.x)
    return a.xx * b + a.yy * mk2(-b.y, b.x);
}
__device__ __forceinline__ v2f mulnegi(v2f z) { return mk2(z.y, -z.x); }   // -i*z
__device__ __forceinline__ v2f mulposi(v2f z) { return mk2(-z.y, z.x); }   // +i*z

// ---- radix-4 butterflies (same algebra as verified R1..R14) ----
__device__ __forceinline__ void bfly4(v2f& a, v2f& b, v2f& c, v2f& d,
                                      v2f w1, v2f w2, v2f w3) {
    v2f apc = a + c, amc = a - c;
    v2f bpd = b + d, bmd = b - d;
    v2f nib = mulnegi(bmd);
    a = apc + bpd;
    b = cmul(apc - bpd, w2);
    c = cmul(amc + nib, w1);
    d = cmul(amc - nib, w3);
}
__device__ __forceinline__ void bfly4_nw(v2f& a, v2f& b, v2f& c, v2f& d) {
    v2f apc = a + c, amc = a - c;
    v2f bpd = b + d, bmd = b - d;
    v2f nib = mulnegi(bmd);
    a = apc + bpd;
    b = apc - bpd;
    c = amc + nib;
    d = amc - nib;
}
__device__ __forceinline__ void ibfly4(v2f& a, v2f& b, v2f& c, v2f& d,
                                       v2f w1t, v2f w2t) {
    v2f w1 = mk2(w1t.x, -w1t.y);
    v2f w2 = mk2(w2t.x, -w2t.y);
    v2f bt = cmul(b, w2), dt = cmul(d, w2);
    v2f A = a + bt, Bb = a - bt;
    v2f C = c + dt, Dd = c - dt;
    v2f Cw = cmul(C, w1);
    v2f Dw = mulposi(cmul(Dd, w1));
    a = A + Cw;  c = A - Cw;
    b = Bb + Dw; d = Bb - Dw;
}
__device__ __forceinline__ void ibfly4_nw(v2f& a, v2f& b, v2f& c, v2f& d) {
    v2f A = a + b, Bb = a - b;
    v2f C = c + d, Dd = c - d;
    v2f Dw = mulposi(Dd);
    a = A + C;  c = A - C;
    b = Bb + Dw; d = Bb - Dw;
}

// ---- g01 half-passes (verified R10..R14) ----
__device__ __forceinline__ void fwd_g01_half(v2f rh[16], const int t, const int par,
                                             const v2f* __restrict__ tw) {
#pragma unroll
    for (int m0 = 0; m0 < 4; ++m0) {
        const int i = t + 512 * par + 1024 * m0;
        bfly4(rh[m0], rh[m0 + 4], rh[m0 + 8], rh[m0 + 12], tw[i], tw[2 * i], tw[3 * i]);
    }
    {
        const int ig = (t + 512 * par) * 4;
        const v2f w1 = tw[ig], w2 = tw[2 * ig], w3 = tw[3 * ig];
#pragma unroll
        for (int a = 0; a < 4; ++a)
            bfly4(rh[4 * a], rh[4 * a + 1], rh[4 * a + 2], rh[4 * a + 3], w1, w2, w3);
    }
}
__device__ __forceinline__ void inv_g01_half(v2f rh[16], const int t, const int par,
                                             const v2f* __restrict__ tw) {
    {
        const int ig = (t + 512 * par) * 4;
        const v2f w1 = tw[ig], w2 = tw[2 * ig];
#pragma unroll
        for (int a = 0; a < 4; ++a)
            ibfly4(rh[4 * a], rh[4 * a + 1], rh[4 * a + 2], rh[4 * a + 3], w1, w2);
    }
#pragma unroll
    for (int m0 = 0; m0 < 4; ++m0) {
        const int i = t + 512 * par + 1024 * m0;
        ibfly4(rh[m0], rh[m0 + 4], rh[m0 + 8], rh[m0 + 12], tw[i], tw[2 * i]);
    }
}

// ---- per-s mid half (kfft only; verified R10..R14) ----
__device__ __forceinline__ void fwd_mid_half(v2f rh[16], v2f* lds2,
                                             const int w, const int l, const int s,
                                             const v2f* __restrict__ tw) {
    const int base = w * 2048 + 1024 * s;
#pragma unroll
    for (int jj = 0; jj < 16; ++jj)
        rh[jj] = lds2[SWZ2(base + 64 * jj + l)];
#pragma unroll
    for (int j0 = 0; j0 < 4; ++j0) {
        const int i1 = 1024 * j0 + 16 * l;
        bfly4(rh[j0], rh[j0 + 4], rh[j0 + 8], rh[j0 + 12], tw[i1], tw[2 * i1], tw[3 * i1]);
    }
    {
        const int i2 = 64 * l;
        const v2f w1 = tw[i2], w2 = tw[2 * i2], w3 = tw[3 * i2];
#pragma unroll
        for (int g = 0; g < 4; ++g)
            bfly4(rh[4 * g], rh[4 * g + 1], rh[4 * g + 2], rh[4 * g + 3], w1, w2, w3);
    }
#pragma unroll
    for (int jj = 0; jj < 16; ++jj)
        lds2[SWZ2(base + 64 * jj + l)] = rh[jj];
    {
        const int lo = 64 * (l >> 2) + (l & 3);
#pragma unroll
        for (int jj = 0; jj < 16; ++jj)
            rh[jj] = lds2[SWZ2(base + lo + 4 * jj)];
    }
#pragma unroll
    for (int j0 = 0; j0 < 4; ++j0) {
        const int i3 = 1024 * j0 + 256 * (l & 3);
        bfly4(rh[j0], rh[j0 + 4], rh[j0 + 8], rh[j0 + 12], tw[i3], tw[2 * i3], tw[3 * i3]);
    }
    {
        const int i4 = 1024 * (l & 3);
        const v2f w1 = tw[i4], w2 = tw[2 * i4], w3 = tw[3 * i4];
#pragma unroll
        for (int g = 0; g < 4; ++g)
            bfly4(rh[4 * g], rh[4 * g + 1], rh[4 * g + 2], rh[4 * g + 3], w1, w2, w3);
    }
    {
        const int lo = 64 * (l >> 2) + (l & 3);
#pragma unroll
        for (int jj = 0; jj < 16; ++jj)
            lds2[SWZ2(base + lo + 4 * jj)] = rh[jj];
    }
#pragma unroll
    for (int jj = 0; jj < 16; ++jj)
        rh[jj] = lds2[SWZ2(base + 16 * l + jj)];
#pragma unroll
    for (int g = 0; g < 4; ++g)
        bfly4_nw(rh[4 * g], rh[4 * g + 1], rh[4 * g + 2], rh[4 * g + 3]);
}

// ---- conv fused middle (R14 champion structure; v2f packed math) ----
__device__ __forceinline__ void conv_mid_fused(v2f* lds2,
                                               const int t, const int w, const int l,
                                               const float4* __restrict__ kf4,
                                               const v2f* __restrict__ tw) {
    const int base = w * 2048;
    const int lo = 64 * (l >> 2) + (l & 3);
    v2f r0[16], r1[16];
#pragma unroll
    for (int jj = 0; jj < 16; ++jj) {
        r0[jj] = lds2[SWZ2(base + 64 * jj + l)];
        r1[jj] = lds2[SWZ2(base + 1024 + 64 * jj + l)];
    }
    // fwd stage q=256
#pragma unroll
    for (int j0 = 0; j0 < 4; ++j0) {
        const int i1 = 1024 * j0 + 16 * l;
        const v2f w1 = tw[i1], w2 = tw[2 * i1], w3 = tw[3 * i1];
        bfly4(r0[j0], r0[j0 + 4], r0[j0 + 8], r0[j0 + 12], w1, w2, w3);
        bfly4(r1[j0], r1[j0 + 4], r1[j0 + 8], r1[j0 + 12], w1, w2, w3);
    }
    // fwd stage q=64 (uniform)
    {
        const int i2 = 64 * l;
        const v2f w1 = tw[i2], w2 = tw[2 * i2], w3 = tw[3 * i2];
#pragma unroll
        for (int g = 0; g < 4; ++g) {
            bfly4(r0[4 * g], r0[4 * g + 1], r0[4 * g + 2], r0[4 * g + 3], w1, w2, w3);
            bfly4(r1[4 * g], r1[4 * g + 1], r1[4 * g + 2], r1[4 * g + 3], w1, w2, w3);
        }
    }
    // W1 -> W2
#pragma unroll
    for (int jj = 0; jj < 16; ++jj) {
        lds2[SWZ2(base + 64 * jj + l)] = r0[jj];
        lds2[SWZ2(base + 1024 + 64 * jj + l)] = r1[jj];
    }
#pragma unroll
    for (int jj = 0; jj < 16; ++jj) {
        r0[jj] = lds2[SWZ2(base + lo + 4 * jj)];
        r1[jj] = lds2[SWZ2(base + 1024 + lo + 4 * jj)];
    }
    // fwd stage q=16
#pragma unroll
    for (int j0 = 0; j0 < 4; ++j0) {
        const int i3 = 1024 * j0 + 256 * (l & 3);
        const v2f w1 = tw[i3], w2 = tw[2 * i3], w3 = tw[3 * i3];
        bfly4(r0[j0], r0[j0 + 4], r0[j0 + 8], r0[j0 + 12], w1, w2, w3);
        bfly4(r1[j0], r1[j0 + 4], r1[j0 + 8], r1[j0 + 12], w1, w2, w3);
    }
    // fwd stage q=4 (uniform)
    {
        const int i4 = 1024 * (l & 3);
        const v2f w1 = tw[i4], w2 = tw[2 * i4], w3 = tw[3 * i4];
#pragma unroll
        for (int g = 0; g < 4; ++g) {
            bfly4(r0[4 * g], r0[4 * g + 1], r0[4 * g + 2], r0[4 * g + 3], w1, w2, w3);
            bfly4(r1[4 * g], r1[4 * g + 1], r1[4 * g + 2], r1[4 * g + 3], w1, w2, w3);
        }
    }
    // W2 -> W3
#pragma unroll
    for (int jj = 0; jj < 16; ++jj) {
        lds2[SWZ2(base + lo + 4 * jj)] = r0[jj];
        lds2[SWZ2(base + 1024 + lo + 4 * jj)] = r1[jj];
    }
#pragma unroll
    for (int jj = 0; jj < 16; ++jj) {
        r0[jj] = lds2[SWZ2(base + 16 * l + jj)];
        r1[jj] = lds2[SWZ2(base + 1024 + 16 * l + jj)];
    }
    // fwd stage q=1
#pragma unroll
    for (int g = 0; g < 4; ++g) {
        bfly4_nw(r0[4 * g], r0[4 * g + 1], r0[4 * g + 2], r0[4 * g + 3]);
        bfly4_nw(r1[4 * g], r1[4 * g + 1], r1[4 * g + 2], r1[4 * g + 3]);
    }
    // pointwise multiply (thread-linear W3 order; Kf PRE-SCALED by 1/N)
#pragma unroll
    for (int q = 0; q < 8; ++q) {
        const float4 k0 = kf4[16 * t + q];
        const float4 k1 = kf4[16 * t + 8 + q];
        r0[2 * q]     = cmul(r0[2 * q],     mk2(k0.x, k0.y));
        r0[2 * q + 1] = cmul(r0[2 * q + 1], mk2(k0.z, k0.w));
        r1[2 * q]     = cmul(r1[2 * q],     mk2(k1.x, k1.y));
        r1[2 * q + 1] = cmul(r1[2 * q + 1], mk2(k1.z, k1.w));
    }
    // inv stage q=1
#pragma unroll
    for (int g = 0; g < 4; ++g) {
        ibfly4_nw(r0[4 * g], r0[4 * g + 1], r0[4 * g + 2], r0[4 * g + 3]);
        ibfly4_nw(r1[4 * g], r1[4 * g + 1], r1[4 * g + 2], r1[4 * g + 3]);
    }
    // W3 -> W2
#pragma unroll
    for (int jj = 0; jj < 16; ++jj) {
        lds2[SWZ2(base + 16 * l + jj)] = r0[jj];
        lds2[SWZ2(base + 1024 + 16 * l + jj)] = r1[jj];
    }
#pragma unroll
    for (int jj = 0; jj < 16; ++jj) {
        r0[jj] = lds2[SWZ2(base + lo + 4 * jj)];
        r1[jj] = lds2[SWZ2(base + 1024 + lo + 4 * jj)];
    }
    // inv stage q=4 (uniform), then q=16
    {
        const int i4 = 1024 * (l & 3);
        const v2f w1 = tw[i4], w2 = tw[2 * i4];
#pragma unroll
        for (int g = 0; g < 4; ++g) {
            ibfly4(r0[4 * g], r0[4 * g + 1], r0[4 * g + 2], r0[4 * g + 3], w1, w2);
            ibfly4(r1[4 * g], r1[4 * g + 1], r1[4 * g + 2], r1[4 * g + 3], w1, w2);
        }
    }
#pragma unroll
    for (int j0 = 0; j0 < 4; ++j0) {
        const int i3 = 1024 * j0 + 256 * (l & 3);
        const v2f w1 = tw[i3], w2 = tw[2 * i3];
        ibfly4(r0[j0], r0[j0 + 4], r0[j0 + 8], r0[j0 + 12], w1, w2);
        ibfly4(r1[j0], r1[j0 + 4], r1[j0 + 8], r1[j0 + 12], w1, w2);
    }
    // W2 -> W1
#pragma unroll
    for (int jj = 0; jj < 16; ++jj) {
        lds2[SWZ2(base + lo + 4 * jj)] = r0[jj];
        lds2[SWZ2(base + 1024 + lo + 4 * jj)] = r1[jj];
    }
#pragma unroll
    for (int jj = 0; jj < 16; ++jj) {
        r0[jj] = lds2[SWZ2(base + 64 * jj + l)];
        r1[jj] = lds2[SWZ2(base + 1024 + 64 * jj + l)];
    }
    // inv stage q=64 (uniform), then q=256
    {
        const int i2 = 64 * l;
        const v2f w1 = tw[i2], w2 = tw[2 * i2];
#pragma unroll
        for (int g = 0; g < 4; ++g) {
            ibfly4(r0[4 * g], r0[4 * g + 1], r0[4 * g + 2], r0[4 * g + 3], w1, w2);
            ibfly4(r1[4 * g], r1[4 * g + 1], r1[4 * g + 2], r1[4 * g + 3], w1, w2);
        }
    }
#pragma unroll
    for (int j0 = 0; j0 < 4; ++j0) {
        const int i1 = 1024 * j0 + 16 * l;
        const v2f w1 = tw[i1], w2 = tw[2 * i1];
        ibfly4(r0[j0], r0[j0 + 4], r0[j0 + 8], r0[j0 + 12], w1, w2);
        ibfly4(r1[j0], r1[j0 + 4], r1[j0 + 8], r1[j0 + 12], w1, w2);
    }
    // write W1 both (caller issues workgroup barrier)
#pragma unroll
    for (int jj = 0; jj < 16; ++jj) {
        lds2[SWZ2(base + 64 * jj + l)] = r0[jj];
        lds2[SWZ2(base + 1024 + 64 * jj + l)] = r1[jj];
    }
}

__device__ __forceinline__ float ftanh(float x) {
    float e = __expf(2.0f * x);
    return 1.0f - 2.0f * __builtin_amdgcn_rcpf(e + 1.0f);
}

__global__ void twiddle_init(float2* __restrict__ tw) {
    int t = blockIdx.x * blockDim.x + threadIdx.x;
    if (t < FFT_N) {
        float ang = -2.0f * 3.14159265358979323846f * (float)t / (float)FFT_N;
        float sv, cv;
        sincosf(ang, &sv, &cv);
        tw[t] = make_float2(cv, sv);
    }
}

// Forward FFT of (k_h + dh*delta) -> Kf[h], thread-linear W3 order,
// PRE-SCALED by 1/N (verified R12..R14).
__global__ __launch_bounds__(NT) void kfft_kernel(const float* __restrict__ k,
                                                  const float* __restrict__ D,
                                                  const v2f* __restrict__ tw,
                                                  float2* __restrict__ Kf) {
    __shared__ v2f lds2[FFT_N];   // 131072 B
    const int h = blockIdx.x;
    const int t = threadIdx.x;
    const int w = t >> 6, l = t & 63;
    const float* krow = k + (size_t)h * FFT_N;
    const float dh = D[h * (H_DIM + 1)];
#pragma unroll
    for (int par = 0; par < 2; ++par) {
        v2f rh[16];
#pragma unroll
        for (int m = 0; m < 16; ++m)
            rh[m] = mk2(krow[t + 512 * par + 1024 * m], 0.f);
        if (par == 0 && t == 0) rh[0].x += dh;   // fold diag(D) into k's 0th tap
        fwd_g01_half(rh, t, par, tw);
#pragma unroll
        for (int m = 0; m < 16; ++m) {
            const int e = t + 512 * par + 1024 * m;
            lds2[SWZ2(e)] = rh[m];
        }
    }
    __syncthreads();
    const float invN = 1.0f / (float)FFT_N;
    float4* out4 = (float4*)(Kf + (size_t)h * FFT_N);
#pragma unroll
    for (int s = 0; s < 2; ++s) {
        v2f rh[16];
        fwd_mid_half(rh, lds2, w, l, s, tw);
#pragma unroll
        for (int q = 0; q < 8; ++q)
            out4[16 * t + 8 * s + q] =
                make_float4(rh[2 * q].x * invN, rh[2 * q].y * invN,
                            rh[2 * q + 1].x * invN, rh[2 * q + 1].y * invN);
    }
}

// Batch rows (2p,h) and (2p+1,h) packed as z = u0 + i*u1.
__global__ __launch_bounds__(NT) void conv_kernel(const float* __restrict__ u,
                                                  const v2f* __restrict__ tw,
                                                  const float2* __restrict__ Kf,
                                                  float* __restrict__ out) {
    __shared__ v2f lds2[FFT_N];   // 131072 B
    const int raw = blockIdx.x;
    const int vb = ((raw & 7) << 7) + (raw >> 3);   // XCD-chunked bijection
    const int h = vb >> 2;
    const int p = vb & 3;
    const int t = threadIdx.x;
    const int w = t >> 6, l = t & 63;
    const size_t row0 = ((size_t)(2 * p) * H_DIM + h) * FFT_N;
    const size_t row1 = row0 + (size_t)H_DIM * FFT_N;
    const float* u0 = u + row0;
    const float* u1 = u + row1;

    // entry: two independent 16-register half-passes (verified R10..R14)
#pragma unroll
    for (int par = 0; par < 2; ++par) {
        v2f rh[16];
#pragma unroll
        for (int m = 0; m < 16; ++m) {
            const int n = t + 512 * par + 1024 * m;
            rh[m] = mk2(u0[n], u1[n]);
        }
        fwd_g01_half(rh, t, par, tw);
#pragma unroll
        for (int m = 0; m < 16; ++m) {
            const int e = t + 512 * par + 1024 * m;
            lds2[SWZ2(e)] = rh[m];
        }
    }
    __syncthreads();

    // fused full-width middle (fwd + pointwise + inv)
    conv_mid_fused(lds2, t, w, l, (const float4*)(Kf + (size_t)h * FFT_N), tw);
    __syncthreads();

    // exit: per-parity half-passes
    float* o0 = out + row0;
    float* o1 = out + row1;
#pragma unroll
    for (int par = 0; par < 2; ++par) {
        v2f rh[16];
#pragma unroll
        for (int m = 0; m < 16; ++m) {
            const int e = t + 512 * par + 1024 * m;
            rh[m] = lds2[SWZ2(e)];
        }
        inv_g01_half(rh, t, par, tw);
#pragma unroll
        for (int m = 0; m < 16; ++m) {
            const int n = t + 512 * par + 1024 * m;
            o0[n] = ftanh(rh[m].x);
            o1[n] = ftanh(rh[m].y);
        }
    }
}

extern "C" void kernel_launch(void* const* d_in, const int* in_sizes, int n_in,
                              void* d_out, int out_size, void* d_ws, size_t ws_size,
                              hipStream_t stream) {
    const float* u = (const float*)d_in[0];   // (B,H,L) f32
    const float* k = (const float*)d_in[1];   // (H,L)   f32
    const float* D = (const float*)d_in[2];   // (H,H)   f32
    float* out = (float*)d_out;

    float2* tw = (float2*)d_ws;               // 16384 float2 = 128 KiB
    float2* Kf = tw + FFT_N;                  // 256*16384 float2 = 32 MiB

    twiddle_init<<<FFT_N / 256, 256, 0, stream>>>(tw);
    kfft_kernel<<<H_DIM, NT, 0, stream>>>(k, D, (const v2f*)tw, Kf);
    conv_kernel<<<(B_DIM / 2) * H_DIM, NT, 0, stream>>>(u, (const v2f*)tw, Kf, out);
}

// Round 17
// 194.786 us; speedup vs baseline: 1.3517x; 1.0441x over previous
//
#include <hip/hip_runtime.h>
#include <math.h>

#define FFT_N 16384
#define NT 512
#define B_DIM 8
#define H_DIM 256

// Single float2 plane (128 KiB), b64 DS ops. XOR swizzle in float2-index
// space: bijective, keeps each wave's 2048-element region closed, and holds
// every access map at <=4 lanes per bank-pair (= b64 wave capacity):
//   nA (t+512j), W1 (64jj+l), W2 (64(l>>2)+4jj+(l&3)), W3 (16l+jj)  [hand-checked]
#define SWZ2(a) ((a) ^ (((a) >> 5) & 15) ^ (((a) >> 9) & 1))

// No wave-local fences: per-wave DS in-order + compiler alias ordering,
// HW-validated in R13 (absmax bit-identical). Cross-wave points keep
// __syncthreads.
//
// Champion structure (R14, 177.5 us/dispatch). R15 (NT=1024) and R16
// (packed v2f) both regressed and falsified their theories; reverting.

__device__ __forceinline__ float2 cmul(float2 a, float2 b) {
    return make_float2(a.x * b.x - a.y * b.y, a.x * b.y + a.y * b.x);
}
__device__ __forceinline__ float2 cadd(float2 a, float2 b) { return make_float2(a.x + b.x, a.y + b.y); }
__device__ __forceinline__ float2 csub(float2 a, float2 b) { return make_float2(a.x - b.x, a.y - b.y); }
__device__ __forceinline__ float2 mulnegi(float2 z) { return make_float2(z.y, -z.x); }   // -i*z
__device__ __forceinline__ float2 mulposi(float2 z) { return make_float2(-z.y, z.x); }   // +i*z

// ---- radix-4 butterflies (verified R1..R14) ----
__device__ __forceinline__ void bfly4(float2& a, float2& b, float2& c, float2& d,
                                      float2 w1, float2 w2, float2 w3) {
    float2 apc = cadd(a, c), amc = csub(a, c);
    float2 bpd = cadd(b, d), bmd = csub(b, d);
    float2 nib = mulnegi(bmd);
    a = cadd(apc, bpd);
    b = cmul(csub(apc, bpd), w2);
    c = cmul(cadd(amc, nib), w1);
    d = cmul(csub(amc, nib), w3);
}
__device__ __forceinline__ void bfly4_nw(float2& a, float2& b, float2& c, float2& d) {
    float2 apc = cadd(a, c), amc = csub(a, c);
    float2 bpd = cadd(b, d), bmd = csub(b, d);
    float2 nib = mulnegi(bmd);
    a = cadd(apc, bpd);
    b = csub(apc, bpd);
    c = cadd(amc, nib);
    d = csub(amc, nib);
}
__device__ __forceinline__ void ibfly4(float2& a, float2& b, float2& c, float2& d,
                                       float2 w1t, float2 w2t) {
    float2 w1 = make_float2(w1t.x, -w1t.y);
    float2 w2 = make_float2(w2t.x, -w2t.y);
    float2 bt = cmul(b, w2), dt = cmul(d, w2);
    float2 A = cadd(a, bt), Bb = csub(a, bt);
    float2 C = cadd(c, dt), Dd = csub(c, dt);
    float2 Cw = cmul(C, w1);
    float2 Dw = mulposi(cmul(Dd, w1));
    a = cadd(A, Cw);  c = csub(A, Cw);
    b = cadd(Bb, Dw); d = csub(Bb, Dw);
}
__device__ __forceinline__ void ibfly4_nw(float2& a, float2& b, float2& c, float2& d) {
    float2 A = cadd(a, b), Bb = csub(a, b);
    float2 C = cadd(c, d), Dd = csub(c, d);
    float2 Dw = mulposi(Dd);
    a = cadd(A, C);  c = csub(A, C);
    b = cadd(Bb, Dw); d = csub(Bb, Dw);
}

// ---- g01 half-passes (verified R10..R14) ----
__device__ __forceinline__ void fwd_g01_half(float2 rh[16], const int t, const int par,
                                             const float2* __restrict__ tw) {
#pragma unroll
    for (int m0 = 0; m0 < 4; ++m0) {
        const int i = t + 512 * par + 1024 * m0;
        bfly4(rh[m0], rh[m0 + 4], rh[m0 + 8], rh[m0 + 12], tw[i], tw[2 * i], tw[3 * i]);
    }
    {
        const int ig = (t + 512 * par) * 4;
        const float2 w1 = tw[ig], w2 = tw[2 * ig], w3 = tw[3 * ig];
#pragma unroll
        for (int a = 0; a < 4; ++a)
            bfly4(rh[4 * a], rh[4 * a + 1], rh[4 * a + 2], rh[4 * a + 3], w1, w2, w3);
    }
}
__device__ __forceinline__ void inv_g01_half(float2 rh[16], const int t, const int par,
                                             const float2* __restrict__ tw) {
    {
        const int ig = (t + 512 * par) * 4;
        const float2 w1 = tw[ig], w2 = tw[2 * ig];
#pragma unroll
        for (int a = 0; a < 4; ++a)
            ibfly4(rh[4 * a], rh[4 * a + 1], rh[4 * a + 2], rh[4 * a + 3], w1, w2);
    }
#pragma unroll
    for (int m0 = 0; m0 < 4; ++m0) {
        const int i = t + 512 * par + 1024 * m0;
        ibfly4(rh[m0], rh[m0 + 4], rh[m0 + 8], rh[m0 + 12], tw[i], tw[2 * i]);
    }
}

// ---- per-s mid half (kfft only; verified R10..R14) ----
__device__ __forceinline__ void fwd_mid_half(float2 rh[16], float2* lds2,
                                             const int w, const int l, const int s,
                                             const float2* __restrict__ tw) {
    const int base = w * 2048 + 1024 * s;
#pragma unroll
    for (int jj = 0; jj < 16; ++jj)
        rh[jj] = lds2[SWZ2(base + 64 * jj + l)];
#pragma unroll
    for (int j0 = 0; j0 < 4; ++j0) {
        const int i1 = 1024 * j0 + 16 * l;
        bfly4(rh[j0], rh[j0 + 4], rh[j0 + 8], rh[j0 + 12], tw[i1], tw[2 * i1], tw[3 * i1]);
    }
    {
        const int i2 = 64 * l;
        const float2 w1 = tw[i2], w2 = tw[2 * i2], w3 = tw[3 * i2];
#pragma unroll
        for (int g = 0; g < 4; ++g)
            bfly4(rh[4 * g], rh[4 * g + 1], rh[4 * g + 2], rh[4 * g + 3], w1, w2, w3);
    }
#pragma unroll
    for (int jj = 0; jj < 16; ++jj)
        lds2[SWZ2(base + 64 * jj + l)] = rh[jj];
    {
        const int lo = 64 * (l >> 2) + (l & 3);
#pragma unroll
        for (int jj = 0; jj < 16; ++jj)
            rh[jj] = lds2[SWZ2(base + lo + 4 * jj)];
    }
#pragma unroll
    for (int j0 = 0; j0 < 4; ++j0) {
        const int i3 = 1024 * j0 + 256 * (l & 3);
        bfly4(rh[j0], rh[j0 + 4], rh[j0 + 8], rh[j0 + 12], tw[i3], tw[2 * i3], tw[3 * i3]);
    }
    {
        const int i4 = 1024 * (l & 3);
        const float2 w1 = tw[i4], w2 = tw[2 * i4], w3 = tw[3 * i4];
#pragma unroll
        for (int g = 0; g < 4; ++g)
            bfly4(rh[4 * g], rh[4 * g + 1], rh[4 * g + 2], rh[4 * g + 3], w1, w2, w3);
    }
    {
        const int lo = 64 * (l >> 2) + (l & 3);
#pragma unroll
        for (int jj = 0; jj < 16; ++jj)
            lds2[SWZ2(base + lo + 4 * jj)] = rh[jj];
    }
#pragma unroll
    for (int jj = 0; jj < 16; ++jj)
        rh[jj] = lds2[SWZ2(base + 16 * l + jj)];
#pragma unroll
    for (int g = 0; g < 4; ++g)
        bfly4_nw(rh[4 * g], rh[4 * g + 1], rh[4 * g + 2], rh[4 * g + 3]);
}

// ---- conv fused middle (R11/R14 champion structure; Kf pre-scaled) ----
__device__ __forceinline__ void conv_mid_fused(float2* lds2,
                                               const int t, const int w, const int l,
                                               const float4* __restrict__ kf4,
                                               const float2* __restrict__ tw) {
    const int base = w * 2048;
    const int lo = 64 * (l >> 2) + (l & 3);
    float2 r0[16], r1[16];
#pragma unroll
    for (int jj = 0; jj < 16; ++jj) {
        r0[jj] = lds2[SWZ2(base + 64 * jj + l)];
        r1[jj] = lds2[SWZ2(base + 1024 + 64 * jj + l)];
    }
    // fwd stage q=256
#pragma unroll
    for (int j0 = 0; j0 < 4; ++j0) {
        const int i1 = 1024 * j0 + 16 * l;
        const float2 w1 = tw[i1], w2 = tw[2 * i1], w3 = tw[3 * i1];
        bfly4(r0[j0], r0[j0 + 4], r0[j0 + 8], r0[j0 + 12], w1, w2, w3);
        bfly4(r1[j0], r1[j0 + 4], r1[j0 + 8], r1[j0 + 12], w1, w2, w3);
    }
    // fwd stage q=64 (uniform)
    {
        const int i2 = 64 * l;
        const float2 w1 = tw[i2], w2 = tw[2 * i2], w3 = tw[3 * i2];
#pragma unroll
        for (int g = 0; g < 4; ++g) {
            bfly4(r0[4 * g], r0[4 * g + 1], r0[4 * g + 2], r0[4 * g + 3], w1, w2, w3);
            bfly4(r1[4 * g], r1[4 * g + 1], r1[4 * g + 2], r1[4 * g + 3], w1, w2, w3);
        }
    }
    // W1 -> W2
#pragma unroll
    for (int jj = 0; jj < 16; ++jj) {
        lds2[SWZ2(base + 64 * jj + l)] = r0[jj];
        lds2[SWZ2(base + 1024 + 64 * jj + l)] = r1[jj];
    }
#pragma unroll
    for (int jj = 0; jj < 16; ++jj) {
        r0[jj] = lds2[SWZ2(base + lo + 4 * jj)];
        r1[jj] = lds2[SWZ2(base + 1024 + lo + 4 * jj)];
    }
    // fwd stage q=16
#pragma unroll
    for (int j0 = 0; j0 < 4; ++j0) {
        const int i3 = 1024 * j0 + 256 * (l & 3);
        const float2 w1 = tw[i3], w2 = tw[2 * i3], w3 = tw[3 * i3];
        bfly4(r0[j0], r0[j0 + 4], r0[j0 + 8], r0[j0 + 12], w1, w2, w3);
        bfly4(r1[j0], r1[j0 + 4], r1[j0 + 8], r1[j0 + 12], w1, w2, w3);
    }
    // fwd stage q=4 (uniform)
    {
        const int i4 = 1024 * (l & 3);
        const float2 w1 = tw[i4], w2 = tw[2 * i4], w3 = tw[3 * i4];
#pragma unroll
        for (int g = 0; g < 4; ++g) {
            bfly4(r0[4 * g], r0[4 * g + 1], r0[4 * g + 2], r0[4 * g + 3], w1, w2, w3);
            bfly4(r1[4 * g], r1[4 * g + 1], r1[4 * g + 2], r1[4 * g + 3], w1, w2, w3);
        }
    }
    // W2 -> W3
#pragma unroll
    for (int jj = 0; jj < 16; ++jj) {
        lds2[SWZ2(base + lo + 4 * jj)] = r0[jj];
        lds2[SWZ2(base + 1024 + lo + 4 * jj)] = r1[jj];
    }
#pragma unroll
    for (int jj = 0; jj < 16; ++jj) {
        r0[jj] = lds2[SWZ2(base + 16 * l + jj)];
        r1[jj] = lds2[SWZ2(base + 1024 + 16 * l + jj)];
    }
    // fwd stage q=1
#pragma unroll
    for (int g = 0; g < 4; ++g) {
        bfly4_nw(r0[4 * g], r0[4 * g + 1], r0[4 * g + 2], r0[4 * g + 3]);
        bfly4_nw(r1[4 * g], r1[4 * g + 1], r1[4 * g + 2], r1[4 * g + 3]);
    }
    // pointwise multiply (thread-linear W3 order; Kf PRE-SCALED by 1/N)
#pragma unroll
    for (int q = 0; q < 8; ++q) {
        const float4 k0 = kf4[16 * t + q];
        const float4 k1 = kf4[16 * t + 8 + q];
        float2 z;
        z = r0[2 * q];
        r0[2 * q]     = make_float2(z.x * k0.x - z.y * k0.y, z.x * k0.y + z.y * k0.x);
        z = r0[2 * q + 1];
        r0[2 * q + 1] = make_float2(z.x * k0.z - z.y * k0.w, z.x * k0.w + z.y * k0.z);
        z = r1[2 * q];
        r1[2 * q]     = make_float2(z.x * k1.x - z.y * k1.y, z.x * k1.y + z.y * k1.x);
        z = r1[2 * q + 1];
        r1[2 * q + 1] = make_float2(z.x * k1.z - z.y * k1.w, z.x * k1.w + z.y * k1.z);
    }
    // inv stage q=1
#pragma unroll
    for (int g = 0; g < 4; ++g) {
        ibfly4_nw(r0[4 * g], r0[4 * g + 1], r0[4 * g + 2], r0[4 * g + 3]);
        ibfly4_nw(r1[4 * g], r1[4 * g + 1], r1[4 * g + 2], r1[4 * g + 3]);
    }
    // W3 -> W2
#pragma unroll
    for (int jj = 0; jj < 16; ++jj) {
        lds2[SWZ2(base + 16 * l + jj)] = r0[jj];
        lds2[SWZ2(base + 1024 + 16 * l + jj)] = r1[jj];
    }
#pragma unroll
    for (int jj = 0; jj < 16; ++jj) {
        r0[jj] = lds2[SWZ2(base + lo + 4 * jj)];
        r1[jj] = lds2[SWZ2(base + 1024 + lo + 4 * jj)];
    }
    // inv stage q=4 (uniform), then q=16
    {
        const int i4 = 1024 * (l & 3);
        const float2 w1 = tw[i4], w2 = tw[2 * i4];
#pragma unroll
        for (int g = 0; g < 4; ++g) {
            ibfly4(r0[4 * g], r0[4 * g + 1], r0[4 * g + 2], r0[4 * g + 3], w1, w2);
            ibfly4(r1[4 * g], r1[4 * g + 1], r1[4 * g + 2], r1[4 * g + 3], w1, w2);
        }
    }
#pragma unroll
    for (int j0 = 0; j0 < 4; ++j0) {
        const int i3 = 1024 * j0 + 256 * (l & 3);
        const float2 w1 = tw[i3], w2 = tw[2 * i3];
        ibfly4(r0[j0], r0[j0 + 4], r0[j0 + 8], r0[j0 + 12], w1, w2);
        ibfly4(r1[j0], r1[j0 + 4], r1[j0 + 8], r1[j0 + 12], w1, w2);
    }
    // W2 -> W1
#pragma unroll
    for (int jj = 0; jj < 16; ++jj) {
        lds2[SWZ2(base + lo + 4 * jj)] = r0[jj];
        lds2[SWZ2(base + 1024 + lo + 4 * jj)] = r1[jj];
    }
#pragma unroll
    for (int jj = 0; jj < 16; ++jj) {
        r0[jj] = lds2[SWZ2(base + 64 * jj + l)];
        r1[jj] = lds2[SWZ2(base + 1024 + 64 * jj + l)];
    }
    // inv stage q=64 (uniform), then q=256
    {
        const int i2 = 64 * l;
        const float2 w1 = tw[i2], w2 = tw[2 * i2];
#pragma unroll
        for (int g = 0; g < 4; ++g) {
            ibfly4(r0[4 * g], r0[4 * g + 1], r0[4 * g + 2], r0[4 * g + 3], w1, w2);
            ibfly4(r1[4 * g], r1[4 * g + 1], r1[4 * g + 2], r1[4 * g + 3], w1, w2);
        }
    }
#pragma unroll
    for (int j0 = 0; j0 < 4; ++j0) {
        const int i1 = 1024 * j0 + 16 * l;
        const float2 w1 = tw[i1], w2 = tw[2 * i1];
        ibfly4(r0[j0], r0[j0 + 4], r0[j0 + 8], r0[j0 + 12], w1, w2);
        ibfly4(r1[j0], r1[j0 + 4], r1[j0 + 8], r1[j0 + 12], w1, w2);
    }
    // write W1 both (caller issues workgroup barrier)
#pragma unroll
    for (int jj = 0; jj < 16; ++jj) {
        lds2[SWZ2(base + 64 * jj + l)] = r0[jj];
        lds2[SWZ2(base + 1024 + 64 * jj + l)] = r1[jj];
    }
}

__device__ __forceinline__ float ftanh(float x) {
    float e = __expf(2.0f * x);
    return 1.0f - 2.0f * __builtin_amdgcn_rcpf(e + 1.0f);
}

__global__ void twiddle_init(float2* __restrict__ tw) {
    int t = blockIdx.x * blockDim.x + threadIdx.x;
    if (t < FFT_N) {
        float ang = -2.0f * 3.14159265358979323846f * (float)t / (float)FFT_N;
        float sv, cv;
        sincosf(ang, &sv, &cv);
        tw[t] = make_float2(cv, sv);
    }
}

// Forward FFT of (k_h + dh*delta) -> Kf[h], thread-linear W3 order,
// PRE-SCALED by 1/N (verified R12..R14).
__global__ __launch_bounds__(NT) void kfft_kernel(const float* __restrict__ k,
                                                  const float* __restrict__ D,
                                                  const float2* __restrict__ tw,
                                                  float2* __restrict__ Kf) {
    __shared__ float2 lds2[FFT_N];   // 131072 B
    const int h = blockIdx.x;
    const int t = threadIdx.x;
    const int w = t >> 6, l = t & 63;
    const float* krow = k + (size_t)h * FFT_N;
    const float dh = D[h * (H_DIM + 1)];
#pragma unroll
    for (int par = 0; par < 2; ++par) {
        float2 rh[16];
#pragma unroll
        for (int m = 0; m < 16; ++m)
            rh[m] = make_float2(krow[t + 512 * par + 1024 * m], 0.f);
        if (par == 0 && t == 0) rh[0].x += dh;   // fold diag(D) into k's 0th tap
        fwd_g01_half(rh, t, par, tw);
#pragma unroll
        for (int m = 0; m < 16; ++m) {
            const int e = t + 512 * par + 1024 * m;
            lds2[SWZ2(e)] = rh[m];
        }
    }
    __syncthreads();
    const float invN = 1.0f / (float)FFT_N;
    float4* out4 = (float4*)(Kf + (size_t)h * FFT_N);
#pragma unroll
    for (int s = 0; s < 2; ++s) {
        float2 rh[16];
        fwd_mid_half(rh, lds2, w, l, s, tw);
#pragma unroll
        for (int q = 0; q < 8; ++q)
            out4[16 * t + 8 * s + q] =
                make_float4(rh[2 * q].x * invN, rh[2 * q].y * invN,
                            rh[2 * q + 1].x * invN, rh[2 * q + 1].y * invN);
    }
}

// Batch rows (2p,h) and (2p+1,h) packed as z = u0 + i*u1.
__global__ __launch_bounds__(NT) void conv_kernel(const float* __restrict__ u,
                                                  const float2* __restrict__ tw,
                                                  const float2* __restrict__ Kf,
                                                  float* __restrict__ out) {
    __shared__ float2 lds2[FFT_N];   // 131072 B
    const int raw = blockIdx.x;
    const int vb = ((raw & 7) << 7) + (raw >> 3);   // XCD-chunked bijection
    const int h = vb >> 2;
    const int p = vb & 3;
    const int t = threadIdx.x;
    const int w = t >> 6, l = t & 63;
    const size_t row0 = ((size_t)(2 * p) * H_DIM + h) * FFT_N;
    const size_t row1 = row0 + (size_t)H_DIM * FFT_N;
    const float* u0 = u + row0;
    const float* u1 = u + row1;

    // entry: two independent 16-register half-passes (verified R10..R14)
#pragma unroll
    for (int par = 0; par < 2; ++par) {
        float2 rh[16];
#pragma unroll
        for (int m = 0; m < 16; ++m) {
            const int n = t + 512 * par + 1024 * m;
            rh[m] = make_float2(u0[n], u1[n]);
        }
        fwd_g01_half(rh, t, par, tw);
#pragma unroll
        for (int m = 0; m < 16; ++m) {
            const int e = t + 512 * par + 1024 * m;
            lds2[SWZ2(e)] = rh[m];
        }
    }
    __syncthreads();

    // fused full-width middle (fwd + pointwise + inv)
    conv_mid_fused(lds2, t, w, l, (const float4*)(Kf + (size_t)h * FFT_N), tw);
    __syncthreads();

    // exit: per-parity half-passes
    float* o0 = out + row0;
    float* o1 = out + row1;
#pragma unroll
    for (int par = 0; par < 2; ++par) {
        float2 rh[16];
#pragma unroll
        for (int m = 0; m < 16; ++m) {
            const int e = t + 512 * par + 1024 * m;
            rh[m] = lds2[SWZ2(e)];
        }
        inv_g01_half(rh, t, par, tw);
#pragma unroll
        for (int m = 0; m < 16; ++m) {
            const int n = t + 512 * par + 1024 * m;
            o0[n] = ftanh(rh[m].x);
            o1[n] = ftanh(rh[m].y);
        }
    }
}

extern "C" void kernel_launch(void* const* d_in, const int* in_sizes, int n_in,
                              void* d_out, int out_size, void* d_ws, size_t ws_size,
                              hipStream_t stream) {
    const float* u = (const float*)d_in[0];   // (B,H,L) f32
    const float* k = (const float*)d_in[1];   // (H,L)   f32
    const float* D = (const float*)d_in[2];   // (H,H)   f32
    float* out = (float*)d_out;

    float2* tw = (float2*)d_ws;               // 16384 float2 = 128 KiB
    float2* Kf = tw + FFT_N;                  // 256*16384 float2 = 32 MiB

    twiddle_init<<<FFT_N / 256, 256, 0, stream>>>(tw);
    kfft_kernel<<<H_DIM, NT, 0, stream>>>(k, D, tw, Kf);
    conv_kernel<<<(B_DIM / 2) * H_DIM, NT, 0, stream>>>(u, tw, Kf, out);
}

// Round 19
// 193.779 us; speedup vs baseline: 1.3587x; 1.0052x over previous
//
#include <hip/hip_runtime.h>
#include <math.h>

#define FFT_N 16384
#define NT 512
#define B_DIM 8
#define H_DIM 256

// Single float2 plane (128 KiB), b64 DS ops. XOR swizzle in float2-index
// space: bijective, keeps each wave's 2048-element region closed, and holds
// every access map at <=4 lanes per bank-pair (= b64 wave capacity):
//   nA (t+512j), W1 (64jj+l), W2 (64(l>>2)+4jj+(l&3)), W3 (16l+jj)  [hand-checked]
#define SWZ2(a) ((a) ^ (((a) >> 5) & 15) ^ (((a) >> 9) & 1))

// No wave-local fences: per-wave DS in-order + compiler alias ordering,
// HW-validated R13/R14/R16/R17 incl. post-timing replay re-validation.
// Cross-wave points keep __syncthreads.
//
// CHAMPION (R14/R17, 177.5 us/dispatch). Falsified levers — do not retry:
//   NT=1024 (x3: 64-VGPR allocator wall -> spill), 64KiB co-residency,
//   Kf L2-prefetch touches (x2), packed v2f math, no-spill phase-split (x2),
//   s_setprio clusters (R18: post-timing RACE — output diverged on replay).

__device__ __forceinline__ float2 cmul(float2 a, float2 b) {
    return make_float2(a.x * b.x - a.y * b.y, a.x * b.y + a.y * b.x);
}
__device__ __forceinline__ float2 cadd(float2 a, float2 b) { return make_float2(a.x + b.x, a.y + b.y); }
__device__ __forceinline__ float2 csub(float2 a, float2 b) { return make_float2(a.x - b.x, a.y - b.y); }
__device__ __forceinline__ float2 mulnegi(float2 z) { return make_float2(z.y, -z.x); }   // -i*z
__device__ __forceinline__ float2 mulposi(float2 z) { return make_float2(-z.y, z.x); }   // +i*z

// ---- radix-4 butterflies (verified R1..R17) ----
__device__ __forceinline__ void bfly4(float2& a, float2& b, float2& c, float2& d,
                                      float2 w1, float2 w2, float2 w3) {
    float2 apc = cadd(a, c), amc = csub(a, c);
    float2 bpd = cadd(b, d), bmd = csub(b, d);
    float2 nib = mulnegi(bmd);
    a = cadd(apc, bpd);
    b = cmul(csub(apc, bpd), w2);
    c = cmul(cadd(amc, nib), w1);
    d = cmul(csub(amc, nib), w3);
}
__device__ __forceinline__ void bfly4_nw(float2& a, float2& b, float2& c, float2& d) {
    float2 apc = cadd(a, c), amc = csub(a, c);
    float2 bpd = cadd(b, d), bmd = csub(b, d);
    float2 nib = mulnegi(bmd);
    a = cadd(apc, bpd);
    b = csub(apc, bpd);
    c = cadd(amc, nib);
    d = csub(amc, nib);
}
__device__ __forceinline__ void ibfly4(float2& a, float2& b, float2& c, float2& d,
                                       float2 w1t, float2 w2t) {
    float2 w1 = make_float2(w1t.x, -w1t.y);
    float2 w2 = make_float2(w2t.x, -w2t.y);
    float2 bt = cmul(b, w2), dt = cmul(d, w2);
    float2 A = cadd(a, bt), Bb = csub(a, bt);
    float2 C = cadd(c, dt), Dd = csub(c, dt);
    float2 Cw = cmul(C, w1);
    float2 Dw = mulposi(cmul(Dd, w1));
    a = cadd(A, Cw);  c = csub(A, Cw);
    b = cadd(Bb, Dw); d = csub(Bb, Dw);
}
__device__ __forceinline__ void ibfly4_nw(float2& a, float2& b, float2& c, float2& d) {
    float2 A = cadd(a, b), Bb = csub(a, b);
    float2 C = cadd(c, d), Dd = csub(c, d);
    float2 Dw = mulposi(Dd);
    a = cadd(A, C);  c = csub(A, C);
    b = cadd(Bb, Dw); d = csub(Bb, Dw);
}

// ---- g01 half-passes (verified R10..R17) ----
__device__ __forceinline__ void fwd_g01_half(float2 rh[16], const int t, const int par,
                                             const float2* __restrict__ tw) {
#pragma unroll
    for (int m0 = 0; m0 < 4; ++m0) {
        const int i = t + 512 * par + 1024 * m0;
        bfly4(rh[m0], rh[m0 + 4], rh[m0 + 8], rh[m0 + 12], tw[i], tw[2 * i], tw[3 * i]);
    }
    {
        const int ig = (t + 512 * par) * 4;
        const float2 w1 = tw[ig], w2 = tw[2 * ig], w3 = tw[3 * ig];
#pragma unroll
        for (int a = 0; a < 4; ++a)
            bfly4(rh[4 * a], rh[4 * a + 1], rh[4 * a + 2], rh[4 * a + 3], w1, w2, w3);
    }
}
__device__ __forceinline__ void inv_g01_half(float2 rh[16], const int t, const int par,
                                             const float2* __restrict__ tw) {
    {
        const int ig = (t + 512 * par) * 4;
        const float2 w1 = tw[ig], w2 = tw[2 * ig];
#pragma unroll
        for (int a = 0; a < 4; ++a)
            ibfly4(rh[4 * a], rh[4 * a + 1], rh[4 * a + 2], rh[4 * a + 3], w1, w2);
    }
#pragma unroll
    for (int m0 = 0; m0 < 4; ++m0) {
        const int i = t + 512 * par + 1024 * m0;
        ibfly4(rh[m0], rh[m0 + 4], rh[m0 + 8], rh[m0 + 12], tw[i], tw[2 * i]);
    }
}

// ---- per-s mid half (kfft only; verified R10..R17) ----
__device__ __forceinline__ void fwd_mid_half(float2 rh[16], float2* lds2,
                                             const int w, const int l, const int s,
                                             const float2* __restrict__ tw) {
    const int base = w * 2048 + 1024 * s;
#pragma unroll
    for (int jj = 0; jj < 16; ++jj)
        rh[jj] = lds2[SWZ2(base + 64 * jj + l)];
#pragma unroll
    for (int j0 = 0; j0 < 4; ++j0) {
        const int i1 = 1024 * j0 + 16 * l;
        bfly4(rh[j0], rh[j0 + 4], rh[j0 + 8], rh[j0 + 12], tw[i1], tw[2 * i1], tw[3 * i1]);
    }
    {
        const int i2 = 64 * l;
        const float2 w1 = tw[i2], w2 = tw[2 * i2], w3 = tw[3 * i2];
#pragma unroll
        for (int g = 0; g < 4; ++g)
            bfly4(rh[4 * g], rh[4 * g + 1], rh[4 * g + 2], rh[4 * g + 3], w1, w2, w3);
    }
#pragma unroll
    for (int jj = 0; jj < 16; ++jj)
        lds2[SWZ2(base + 64 * jj + l)] = rh[jj];
    {
        const int lo = 64 * (l >> 2) + (l & 3);
#pragma unroll
        for (int jj = 0; jj < 16; ++jj)
            rh[jj] = lds2[SWZ2(base + lo + 4 * jj)];
    }
#pragma unroll
    for (int j0 = 0; j0 < 4; ++j0) {
        const int i3 = 1024 * j0 + 256 * (l & 3);
        bfly4(rh[j0], rh[j0 + 4], rh[j0 + 8], rh[j0 + 12], tw[i3], tw[2 * i3], tw[3 * i3]);
    }
    {
        const int i4 = 1024 * (l & 3);
        const float2 w1 = tw[i4], w2 = tw[2 * i4], w3 = tw[3 * i4];
#pragma unroll
        for (int g = 0; g < 4; ++g)
            bfly4(rh[4 * g], rh[4 * g + 1], rh[4 * g + 2], rh[4 * g + 3], w1, w2, w3);
    }
    {
        const int lo = 64 * (l >> 2) + (l & 3);
#pragma unroll
        for (int jj = 0; jj < 16; ++jj)
            lds2[SWZ2(base + lo + 4 * jj)] = rh[jj];
    }
#pragma unroll
    for (int jj = 0; jj < 16; ++jj)
        rh[jj] = lds2[SWZ2(base + 16 * l + jj)];
#pragma unroll
    for (int g = 0; g < 4; ++g)
        bfly4_nw(rh[4 * g], rh[4 * g + 1], rh[4 * g + 2], rh[4 * g + 3]);
}

// ---- conv fused middle (R11/R14 champion structure; Kf pre-scaled) ----
__device__ __forceinline__ void conv_mid_fused(float2* lds2,
                                               const int t, const int w, const int l,
                                               const float4* __restrict__ kf4,
                                               const float2* __restrict__ tw) {
    const int base = w * 2048;
    const int lo = 64 * (l >> 2) + (l & 3);
    float2 r0[16], r1[16];
#pragma unroll
    for (int jj = 0; jj < 16; ++jj) {
        r0[jj] = lds2[SWZ2(base + 64 * jj + l)];
        r1[jj] = lds2[SWZ2(base + 1024 + 64 * jj + l)];
    }
    // fwd stage q=256
#pragma unroll
    for (int j0 = 0; j0 < 4; ++j0) {
        const int i1 = 1024 * j0 + 16 * l;
        const float2 w1 = tw[i1], w2 = tw[2 * i1], w3 = tw[3 * i1];
        bfly4(r0[j0], r0[j0 + 4], r0[j0 + 8], r0[j0 + 12], w1, w2, w3);
        bfly4(r1[j0], r1[j0 + 4], r1[j0 + 8], r1[j0 + 12], w1, w2, w3);
    }
    // fwd stage q=64 (uniform)
    {
        const int i2 = 64 * l;
        const float2 w1 = tw[i2], w2 = tw[2 * i2], w3 = tw[3 * i2];
#pragma unroll
        for (int g = 0; g < 4; ++g) {
            bfly4(r0[4 * g], r0[4 * g + 1], r0[4 * g + 2], r0[4 * g + 3], w1, w2, w3);
            bfly4(r1[4 * g], r1[4 * g + 1], r1[4 * g + 2], r1[4 * g + 3], w1, w2, w3);
        }
    }
    // W1 -> W2
#pragma unroll
    for (int jj = 0; jj < 16; ++jj) {
        lds2[SWZ2(base + 64 * jj + l)] = r0[jj];
        lds2[SWZ2(base + 1024 + 64 * jj + l)] = r1[jj];
    }
#pragma unroll
    for (int jj = 0; jj < 16; ++jj) {
        r0[jj] = lds2[SWZ2(base + lo + 4 * jj)];
        r1[jj] = lds2[SWZ2(base + 1024 + lo + 4 * jj)];
    }
    // fwd stage q=16
#pragma unroll
    for (int j0 = 0; j0 < 4; ++j0) {
        const int i3 = 1024 * j0 + 256 * (l & 3);
        const float2 w1 = tw[i3], w2 = tw[2 * i3], w3 = tw[3 * i3];
        bfly4(r0[j0], r0[j0 + 4], r0[j0 + 8], r0[j0 + 12], w1, w2, w3);
        bfly4(r1[j0], r1[j0 + 4], r1[j0 + 8], r1[j0 + 12], w1, w2, w3);
    }
    // fwd stage q=4 (uniform)
    {
        const int i4 = 1024 * (l & 3);
        const float2 w1 = tw[i4], w2 = tw[2 * i4], w3 = tw[3 * i4];
#pragma unroll
        for (int g = 0; g < 4; ++g) {
            bfly4(r0[4 * g], r0[4 * g + 1], r0[4 * g + 2], r0[4 * g + 3], w1, w2, w3);
            bfly4(r1[4 * g], r1[4 * g + 1], r1[4 * g + 2], r1[4 * g + 3], w1, w2, w3);
        }
    }
    // W2 -> W3
#pragma unroll
    for (int jj = 0; jj < 16; ++jj) {
        lds2[SWZ2(base + lo + 4 * jj)] = r0[jj];
        lds2[SWZ2(base + 1024 + lo + 4 * jj)] = r1[jj];
    }
#pragma unroll
    for (int jj = 0; jj < 16; ++jj) {
        r0[jj] = lds2[SWZ2(base + 16 * l + jj)];
        r1[jj] = lds2[SWZ2(base + 1024 + 16 * l + jj)];
    }
    // fwd stage q=1
#pragma unroll
    for (int g = 0; g < 4; ++g) {
        bfly4_nw(r0[4 * g], r0[4 * g + 1], r0[4 * g + 2], r0[4 * g + 3]);
        bfly4_nw(r1[4 * g], r1[4 * g + 1], r1[4 * g + 2], r1[4 * g + 3]);
    }
    // pointwise multiply (thread-linear W3 order; Kf PRE-SCALED by 1/N)
#pragma unroll
    for (int q = 0; q < 8; ++q) {
        const float4 k0 = kf4[16 * t + q];
        const float4 k1 = kf4[16 * t + 8 + q];
        float2 z;
        z = r0[2 * q];
        r0[2 * q]     = make_float2(z.x * k0.x - z.y * k0.y, z.x * k0.y + z.y * k0.x);
        z = r0[2 * q + 1];
        r0[2 * q + 1] = make_float2(z.x * k0.z - z.y * k0.w, z.x * k0.w + z.y * k0.z);
        z = r1[2 * q];
        r1[2 * q]     = make_float2(z.x * k1.x - z.y * k1.y, z.x * k1.y + z.y * k1.x);
        z = r1[2 * q + 1];
        r1[2 * q + 1] = make_float2(z.x * k1.z - z.y * k1.w, z.x * k1.w + z.y * k1.z);
    }
    // inv stage q=1
#pragma unroll
    for (int g = 0; g < 4; ++g) {
        ibfly4_nw(r0[4 * g], r0[4 * g + 1], r0[4 * g + 2], r0[4 * g + 3]);
        ibfly4_nw(r1[4 * g], r1[4 * g + 1], r1[4 * g + 2], r1[4 * g + 3]);
    }
    // W3 -> W2
#pragma unroll
    for (int jj = 0; jj < 16; ++jj) {
        lds2[SWZ2(base + 16 * l + jj)] = r0[jj];
        lds2[SWZ2(base + 1024 + 16 * l + jj)] = r1[jj];
    }
#pragma unroll
    for (int jj = 0; jj < 16; ++jj) {
        r0[jj] = lds2[SWZ2(base + lo + 4 * jj)];
        r1[jj] = lds2[SWZ2(base + 1024 + lo + 4 * jj)];
    }
    // inv stage q=4 (uniform), then q=16
    {
        const int i4 = 1024 * (l & 3);
        const float2 w1 = tw[i4], w2 = tw[2 * i4];
#pragma unroll
        for (int g = 0; g < 4; ++g) {
            ibfly4(r0[4 * g], r0[4 * g + 1], r0[4 * g + 2], r0[4 * g + 3], w1, w2);
            ibfly4(r1[4 * g], r1[4 * g + 1], r1[4 * g + 2], r1[4 * g + 3], w1, w2);
        }
    }
#pragma unroll
    for (int j0 = 0; j0 < 4; ++j0) {
        const int i3 = 1024 * j0 + 256 * (l & 3);
        const float2 w1 = tw[i3], w2 = tw[2 * i3];
        ibfly4(r0[j0], r0[j0 + 4], r0[j0 + 8], r0[j0 + 12], w1, w2);
        ibfly4(r1[j0], r1[j0 + 4], r1[j0 + 8], r1[j0 + 12], w1, w2);
    }
    // W2 -> W1
#pragma unroll
    for (int jj = 0; jj < 16; ++jj) {
        lds2[SWZ2(base + lo + 4 * jj)] = r0[jj];
        lds2[SWZ2(base + 1024 + lo + 4 * jj)] = r1[jj];
    }
#pragma unroll
    for (int jj = 0; jj < 16; ++jj) {
        r0[jj] = lds2[SWZ2(base + 64 * jj + l)];
        r1[jj] = lds2[SWZ2(base + 1024 + 64 * jj + l)];
    }
    // inv stage q=64 (uniform), then q=256
    {
        const int i2 = 64 * l;
        const float2 w1 = tw[i2], w2 = tw[2 * i2];
#pragma unroll
        for (int g = 0; g < 4; ++g) {
            ibfly4(r0[4 * g], r0[4 * g + 1], r0[4 * g + 2], r0[4 * g + 3], w1, w2);
            ibfly4(r1[4 * g], r1[4 * g + 1], r1[4 * g + 2], r1[4 * g + 3], w1, w2);
        }
    }
#pragma unroll
    for (int j0 = 0; j0 < 4; ++j0) {
        const int i1 = 1024 * j0 + 16 * l;
        const float2 w1 = tw[i1], w2 = tw[2 * i1];
        ibfly4(r0[j0], r0[j0 + 4], r0[j0 + 8], r0[j0 + 12], w1, w2);
        ibfly4(r1[j0], r1[j0 + 4], r1[j0 + 8], r1[j0 + 12], w1, w2);
    }
    // write W1 both (caller issues workgroup barrier)
#pragma unroll
    for (int jj = 0; jj < 16; ++jj) {
        lds2[SWZ2(base + 64 * jj + l)] = r0[jj];
        lds2[SWZ2(base + 1024 + 64 * jj + l)] = r1[jj];
    }
}

__device__ __forceinline__ float ftanh(float x) {
    float e = __expf(2.0f * x);
    return 1.0f - 2.0f * __builtin_amdgcn_rcpf(e + 1.0f);
}

__global__ void twiddle_init(float2* __restrict__ tw) {
    int t = blockIdx.x * blockDim.x + threadIdx.x;
    if (t < FFT_N) {
        float ang = -2.0f * 3.14159265358979323846f * (float)t / (float)FFT_N;
        float sv, cv;
        sincosf(ang, &sv, &cv);
        tw[t] = make_float2(cv, sv);
    }
}

// Forward FFT of (k_h + dh*delta) -> Kf[h], thread-linear W3 order,
// PRE-SCALED by 1/N (verified R12..R17).
__global__ __launch_bounds__(NT) void kfft_kernel(const float* __restrict__ k,
                                                  const float* __restrict__ D,
                                                  const float2* __restrict__ tw,
                                                  float2* __restrict__ Kf) {
    __shared__ float2 lds2[FFT_N];   // 131072 B
    const int h = blockIdx.x;
    const int t = threadIdx.x;
    const int w = t >> 6, l = t & 63;
    const float* krow = k + (size_t)h * FFT_N;
    const float dh = D[h * (H_DIM + 1)];
#pragma unroll
    for (int par = 0; par < 2; ++par) {
        float2 rh[16];
#pragma unroll
        for (int m = 0; m < 16; ++m)
            rh[m] = make_float2(krow[t + 512 * par + 1024 * m], 0.f);
        if (par == 0 && t == 0) rh[0].x += dh;   // fold diag(D) into k's 0th tap
        fwd_g01_half(rh, t, par, tw);
#pragma unroll
        for (int m = 0; m < 16; ++m) {
            const int e = t + 512 * par + 1024 * m;
            lds2[SWZ2(e)] = rh[m];
        }
    }
    __syncthreads();
    const float invN = 1.0f / (float)FFT_N;
    float4* out4 = (float4*)(Kf + (size_t)h * FFT_N);
#pragma unroll
    for (int s = 0; s < 2; ++s) {
        float2 rh[16];
        fwd_mid_half(rh, lds2, w, l, s, tw);
#pragma unroll
        for (int q = 0; q < 8; ++q)
            out4[16 * t + 8 * s + q] =
                make_float4(rh[2 * q].x * invN, rh[2 * q].y * invN,
                            rh[2 * q + 1].x * invN, rh[2 * q + 1].y * invN);
    }
}

// Batch rows (2p,h) and (2p+1,h) packed as z = u0 + i*u1.
__global__ __launch_bounds__(NT) void conv_kernel(const float* __restrict__ u,
                                                  const float2* __restrict__ tw,
                                                  const float2* __restrict__ Kf,
                                                  float* __restrict__ out) {
    __shared__ float2 lds2[FFT_N];   // 131072 B
    const int raw = blockIdx.x;
    const int vb = ((raw & 7) << 7) + (raw >> 3);   // XCD-chunked bijection
    const int h = vb >> 2;
    const int p = vb & 3;
    const int t = threadIdx.x;
    const int w = t >> 6, l = t & 63;
    const size_t row0 = ((size_t)(2 * p) * H_DIM + h) * FFT_N;
    const size_t row1 = row0 + (size_t)H_DIM * FFT_N;
    const float* u0 = u + row0;
    const float* u1 = u + row1;

    // entry: two independent 16-register half-passes (verified R10..R17)
#pragma unroll
    for (int par = 0; par < 2; ++par) {
        float2 rh[16];
#pragma unroll
        for (int m = 0; m < 16; ++m) {
            const int n = t + 512 * par + 1024 * m;
            rh[m] = make_float2(u0[n], u1[n]);
        }
        fwd_g01_half(rh, t, par, tw);
#pragma unroll
        for (int m = 0; m < 16; ++m) {
            const int e = t + 512 * par + 1024 * m;
            lds2[SWZ2(e)] = rh[m];
        }
    }
    __syncthreads();

    // fused full-width middle (fwd + pointwise + inv)
    conv_mid_fused(lds2, t, w, l, (const float4*)(Kf + (size_t)h * FFT_N), tw);
    __syncthreads();

    // exit: per-parity half-passes
    float* o0 = out + row0;
    float* o1 = out + row1;
#pragma unroll
    for (int par = 0; par < 2; ++par) {
        float2 rh[16];
#pragma unroll
        for (int m = 0; m < 16; ++m) {
            const int e = t + 512 * par + 1024 * m;
            rh[m] = lds2[SWZ2(e)];
        }
        inv_g01_half(rh, t, par, tw);
#pragma unroll
        for (int m = 0; m < 16; ++m) {
            const int n = t + 512 * par + 1024 * m;
            o0[n] = ftanh(rh[m].x);
            o1[n] = ftanh(rh[m].y);
        }
    }
}

extern "C" void kernel_launch(void* const* d_in, const int* in_sizes, int n_in,
                              void* d_out, int out_size, void* d_ws, size_t ws_size,
                              hipStream_t stream) {
    const float* u = (const float*)d_in[0];   // (B,H,L) f32
    const float* k = (const float*)d_in[1];   // (H,L)   f32
    const float* D = (const float*)d_in[2];   // (H,H)   f32
    float* out = (float*)d_out;

    float2* tw = (float2*)d_ws;               // 16384 float2 = 128 KiB
    float2* Kf = tw + FFT_N;                  // 256*16384 float2 = 32 MiB

    twiddle_init<<<FFT_N / 256, 256, 0, stream>>>(tw);
    kfft_kernel<<<H_DIM, NT, 0, stream>>>(k, D, tw, Kf);
    conv_kernel<<<(B_DIM / 2) * H_DIM, NT, 0, stream>>>(u, tw, Kf, out);
}